// Round 1
// baseline (10.569 us; speedup 1.0000x reference)
//
#include <hip/hip_runtime.h>

// CombinedLoss_88450556494045 — 5-level annotation assignment.
// N per level: 131072, 65536, 32768, 16384, 8192  (total 253952)
// Output layout (f32 elements), N = 253952:
//   pos      [0,      N)
//   assigned [N,     4N)   (N,3) row-major
//   norm_ann [4N,    7N)   (N,3) row-major
//   ls       [7N,    8N)
//   rs       [8N,    9N)
//   nls      [9N,   10N)
//   nrs      [10N,  11N)
//   levels   [11N,  12N)

#define N_TOTAL 253952
#define INF_VAL 1.0e8f

__global__ __launch_bounds__(256) void assign_levels_kernel(
    const float* __restrict__ ann,
    const float* __restrict__ anc0, const float* __restrict__ anc1,
    const float* __restrict__ anc2, const float* __restrict__ anc3,
    const float* __restrict__ anc4,
    float* __restrict__ out)
{
    __shared__ float4 sA[256];  // {l, m=min(r,l+radius*stride), area=r-l, r}
    __shared__ float  sL[256];  // l (sorted ascending per setup)
    __shared__ float  sC[256];  // cls

    const int b = blockIdx.x;
    int level, blockBase, gBase;
    const float* anc;
    float loC, hiC, stride;
    // TARGET_RATE = 22050/256 = 86.1328125 ; RANGES edges from CLUSTERS midpoints
    if (b < 512)      { level=0; blockBase=0;   gBase=0;      anc=anc0; stride=1.0f;
                        loC=(float)(-1.0*86.1328125);  hiC=(float)(0.525*86.1328125); }
    else if (b < 768) { level=1; blockBase=512; gBase=131072; anc=anc1; stride=2.0f;
                        loC=(float)(0.525*86.1328125); hiC=(float)(1.05*86.1328125); }
    else if (b < 896) { level=2; blockBase=768; gBase=196608; anc=anc2; stride=4.0f;
                        loC=(float)(1.05*86.1328125);  hiC=(float)(2.1*86.1328125); }
    else if (b < 960) { level=3; blockBase=896; gBase=229376; anc=anc3; stride=8.0f;
                        loC=(float)(2.1*86.1328125);   hiC=(float)(4.2*86.1328125); }
    else              { level=4; blockBase=960; gBase=245760; anc=anc4; stride=16.0f;
                        loC=(float)(4.2*86.1328125);   hiC=(float)(1000.0*86.1328125); }

    const int t = threadIdx.x;
    {
        // one annotation per thread (M == 256 == blockDim.x)
        float l = ann[3*t+0], r = ann[3*t+1], c = ann[3*t+2];
        // radius = (cls==0)*4.5 + (cls==1)*2.5
        float radius = (c == 0.0f ? 4.5f : 0.0f) + (c == 1.0f ? 2.5f : 0.0f);
        float limit = l + radius * stride;   // exact product (radius,stride exact)
        float m = fminf(r, limit);
        sA[t] = make_float4(l, m, r - l, r);
        sL[t] = l;
        sC[t] = c;
    }
    __syncthreads();

    const int idxInLevel = (b - blockBase) * 256 + t;
    const float a = anc[idxInLevel];

    // Branchless upper_bound: cnt = #{ j : l_j <= a }  (9 LDS probes, size=256)
    int cnt = 0;
    #pragma unroll
    for (int s = 128; s > 0; s >>= 1) {
        if (sL[cnt + s - 1] <= a) cnt += s;   // max index probed = 254
    }
    cnt += (sL[cnt < 256 ? cnt : 255] <= a && cnt < 256) ? 1 : 0;

    // Window scan descending from cnt-1; any valid annotation has l >= a - 517
    // (r - l <= 6.0*86.1328125 = 516.8 and m <= r). Use 520 for safety margin.
    float best = INF_VAL;
    int bidx = 0;
    const float aMin = a - 520.0f;
    for (int j = cnt - 1; j >= 0; --j) {
        float4 q = sA[j];
        if (q.x < aMin) break;               // sorted: all earlier j also fail
        float lsj = a - q.x;                 // >= 0 guaranteed (j < cnt)
        float rsj = q.w - a;
        float mx  = fmaxf(lsj, rsj);
        bool ok = (a <= q.y) & (mx >= loC) & (mx <= hiC);
        // descending scan + '<=' => smallest j wins ties == argmin-first semantics
        if (ok & (q.z <= best)) { best = q.z; bidx = j; }
    }

    const float4 qb  = sA[bidx];
    const float clsb = sC[bidx];
    const bool  pos  = best < INF_VAL;
    const float clsOut = pos ? clsb : 0.0f;
    const float lb = qb.x, rb = qb.w;
    const float inv = 1.0f / stride;         // stride = 2^i -> exact reciprocal
    const float lsv = a - lb;
    const float rsv = rb - a;
    const int g = gBase + idxInLevel;

    out[g] = pos ? 1.0f : 0.0f;
    float* assigned = out + N_TOTAL;
    assigned[3*g+0] = lb;
    assigned[3*g+1] = rb;
    assigned[3*g+2] = clsOut;
    float* norm = out + 4*N_TOTAL;
    norm[3*g+0] = lb * inv;
    norm[3*g+1] = rb * inv;
    norm[3*g+2] = clsOut;
    out[7*N_TOTAL  + g] = lsv;
    out[8*N_TOTAL  + g] = rsv;
    out[9*N_TOTAL  + g] = lsv * inv;
    out[10*N_TOTAL + g] = rsv * inv;
    out[11*N_TOTAL + g] = (float)(level + 1);
}

extern "C" void kernel_launch(void* const* d_in, const int* in_sizes, int n_in,
                              void* d_out, int out_size, void* d_ws, size_t ws_size,
                              hipStream_t stream) {
    const float* ann = (const float*)d_in[0];
    const float* a0  = (const float*)d_in[1];
    const float* a1  = (const float*)d_in[2];
    const float* a2  = (const float*)d_in[3];
    const float* a3  = (const float*)d_in[4];
    const float* a4  = (const float*)d_in[5];
    float* out = (float*)d_out;

    assign_levels_kernel<<<992, 256, 0, stream>>>(ann, a0, a1, a2, a3, a4, out);
}